// Round 16
// baseline (665.173 us; speedup 1.0000x reference)
//
#include <hip/hip_runtime.h>

typedef unsigned int uint;
typedef unsigned short ushort;
typedef __fp16 half2_t __attribute__((ext_vector_type(2)));
typedef __fp16 half8_t __attribute__((ext_vector_type(8)));
typedef float floatx4 __attribute__((ext_vector_type(4)));

#define SEQ 512
#define BATCH 128
#define HID 128
#define NTAG 32
#define START_TAG 30
#define END_TAG 31

__device__ __forceinline__ float fdot2(uint a, uint b, float c) {
  return __builtin_amdgcn_fdot2(__builtin_bit_cast(half2_t, a),
                                __builtin_bit_cast(half2_t, b), c, false);
}
__device__ __forceinline__ uint packh2(float a, float b) {
  half2_t h = __builtin_amdgcn_cvt_pkrtz(a, b);
  return __builtin_bit_cast(uint, h);
}
__device__ __forceinline__ float frcp(float x) { return __builtin_amdgcn_rcpf(x); }
__device__ __forceinline__ float fexp2(float x) { return __builtin_amdgcn_exp2f(x); }
__device__ __forceinline__ float flog2(float x) { return __builtin_amdgcn_logf(x); }

// Quad butterfly sum via DPP quad_perm (VALU pipe, no LDS).
__device__ __forceinline__ float quad_add(float x) {
  int a = __builtin_bit_cast(int, x);
  int b = __builtin_amdgcn_update_dpp(0, a, 0xB1, 0xF, 0xF, true);
  float y = x + __builtin_bit_cast(float, b);
  int c2 = __builtin_bit_cast(int, y);
  int d2 = __builtin_amdgcn_update_dpp(0, c2, 0x4E, 0xF, 0xF, true);
  return y + __builtin_bit_cast(float, d2);
}
template <int CTRL>
__device__ __forceinline__ float quad_bcast(float x) {
  int a = __builtin_bit_cast(int, x);
  int b = __builtin_amdgcn_update_dpp(0, a, CTRL, 0xF, 0xF, true);
  return __builtin_bit_cast(float, b);
}

// ---------------------------------------------------------------------------
// prep (R23: + sentT transpose + embed fp32->fp16)
// ---------------------------------------------------------------------------
__global__ __launch_bounds__(256) void prep_kernel(
    const float* __restrict__ Wihf, const float* __restrict__ Whhf,
    const float* __restrict__ bihf, const float* __restrict__ bhhf,
    const float* __restrict__ Wihb, const float* __restrict__ Whhb,
    const float* __restrict__ bihb, const float* __restrict__ bhhb,
    const float* __restrict__ Wout, const int* __restrict__ sentence,
    const float* __restrict__ embed,
    uint* __restrict__ wihI, uint* __restrict__ whh,
    uint* __restrict__ woutp, float* __restrict__ biasI,
    int* __restrict__ sentT, uint* __restrict__ embH)
{
  int idx = blockIdx.x * 256 + threadIdx.x;
  if (idx < 65536) {
    int d = idx >> 15, rem = idx & 32767;
    int n = rem >> 6, dw = rem & 63;
    int m = n >> 2, q = n & 3;
    int g = q * 128 + m;
    const float* W = d ? Wihb : Wihf;
    wihI[idx] = packh2(W[g * 128 + 2 * dw], W[g * 128 + 2 * dw + 1]);
  }
  int i2 = idx - 65536;
  if (i2 >= 0 && i2 < 65536) {
    int d = i2 >> 15, rem = i2 & 32767;
    int g = rem >> 6, dw = rem & 63;
    const float* W = d ? Whhb : Whhf;
    whh[i2] = packh2(W[g * 128 + 2 * dw], W[g * 128 + 2 * dw + 1]);
  }
  int i3 = idx - 131072;
  if (i3 >= 0 && i3 < 4096) {
    int k = i3 >> 7, dw = i3 & 127;
    float a, b2;
    if (dw < 64) { a = Wout[k * 256 + 2 * dw]; b2 = Wout[k * 256 + 2 * dw + 1]; }
    else { int j = dw - 64; a = Wout[k * 256 + 128 + 2 * j]; b2 = Wout[k * 256 + 128 + 2 * j + 1]; }
    woutp[i3] = packh2(a, b2);
  }
  int i4 = idx - 135168;
  if (i4 >= 0 && i4 < 1024) {
    int d = i4 >> 9, n = i4 & 511;
    int g = (n & 3) * 128 + (n >> 2);
    biasI[i4] = d ? (bihb[g] + bhhb[g]) : (bihf[g] + bhhf[g]);
  }
  int i5 = idx - 136192;
  if (i5 >= 0 && i5 < 65536) {
    int b = i5 & 127, s = i5 >> 7;
    sentT[i5] = sentence[b * SEQ + s];
  }
  int i6 = idx - 201728;
  if (i6 >= 0 && i6 < 2097152) {
    embH[i6] = packh2(embed[2 * i6], embed[2 * i6 + 1]);
  }
}

// ---------------------------------------------------------------------------
// gemmx core (R22 LDS-staged output; R23 fp16 embed on the ALLT path).
// ---------------------------------------------------------------------------
template <bool ALLT>
__device__ __forceinline__ void gemmx_body(
    const int* __restrict__ sentT, const float* __restrict__ embed,
    const uint* __restrict__ embH,
    const uint* __restrict__ wihI, const float* __restrict__ biasI,
    uint* __restrict__ gatex, int chunk, int blk)
{
  int tl = blk & 127, nb = (blk >> 7) & 3, d = blk >> 9;
  int t = chunk * 128 + tl;
  int s = d ? (511 - t) : t;
  __shared__ int tok[128];
  __shared__ __align__(16) __fp16 tile[128][136];
  int tid = threadIdx.x;
  if (tid < 128) tok[tid] = sentT[s * 128 + tid];
  __syncthreads();

  int w = tid >> 6, lane = tid & 63;
  int q = lane >> 4, r = lane & 15;
  int wr = w >> 1, wc = w & 1;
  int r0 = wr * 64;
  int cl0 = wc * 64;
  int c0 = nb * 128 + cl0;

  floatx4 acc[4][4];
#pragma unroll
  for (int i = 0; i < 4; ++i)
#pragma unroll
    for (int j = 0; j < 4; ++j) acc[i][j] = (floatx4){0.f, 0.f, 0.f, 0.f};

  const uint4* bptr[4];
#pragma unroll
  for (int j = 0; j < 4; ++j)
    bptr[j] = (const uint4*)(wihI + ((size_t)d * 512 + c0 + j * 16 + r) * 64) + q;

  if constexpr (ALLT) {
    const uint4* aptr[4];
#pragma unroll
    for (int i = 0; i < 4; ++i)
      aptr[i] = (const uint4*)embH + (size_t)tok[r0 + i * 16 + r] * 16 + q;
#pragma unroll
    for (int kc = 0; kc < 4; ++kc) {
      half8_t af[4], bf[4];
#pragma unroll
      for (int i = 0; i < 4; ++i)
        af[i] = __builtin_bit_cast(half8_t, aptr[i][kc * 4]);
#pragma unroll
      for (int j = 0; j < 4; ++j)
        bf[j] = __builtin_bit_cast(half8_t, bptr[j][kc * 4]);
#pragma unroll
      for (int i = 0; i < 4; ++i)
#pragma unroll
        for (int j = 0; j < 4; ++j)
          acc[i][j] = __builtin_amdgcn_mfma_f32_16x16x32_f16(af[i], bf[j], acc[i][j], 0, 0, 0);
    }
  } else {
    const float4* aptr[4];
#pragma unroll
    for (int i = 0; i < 4; ++i)
      aptr[i] = (const float4*)(embed + (size_t)tok[r0 + i * 16 + r] * HID) + q * 2;
#pragma unroll
    for (int kc = 0; kc < 4; ++kc) {
      half8_t af[4], bf[4];
#pragma unroll
      for (int i = 0; i < 4; ++i) {
        float4 x0 = aptr[i][kc * 8];
        float4 x1 = aptr[i][kc * 8 + 1];
        uint4 u;
        u.x = packh2(x0.x, x0.y); u.y = packh2(x0.z, x0.w);
        u.z = packh2(x1.x, x1.y); u.w = packh2(x1.z, x1.w);
        af[i] = __builtin_bit_cast(half8_t, u);
      }
#pragma unroll
      for (int j = 0; j < 4; ++j)
        bf[j] = __builtin_bit_cast(half8_t, bptr[j][kc * 4]);
#pragma unroll
      for (int i = 0; i < 4; ++i)
#pragma unroll
        for (int j = 0; j < 4; ++j)
          acc[i][j] = __builtin_amdgcn_mfma_f32_16x16x32_f16(af[i], bf[j], acc[i][j], 0, 0, 0);
    }
  }

#pragma unroll
  for (int j = 0; j < 4; ++j) {
    int cl = cl0 + j * 16 + r;
    float bb = biasI[d * 512 + nb * 128 + cl];
#pragma unroll
    for (int i = 0; i < 4; ++i) {
      int rb = r0 + i * 16 + q * 4;
#pragma unroll
      for (int reg = 0; reg < 4; ++reg)
        tile[rb + reg][cl] = (__fp16)(acc[i][j][reg] + bb);
    }
  }
  __syncthreads();

  size_t dstride = ALLT ? (size_t)65536 * 512 : (size_t)16384 * 512;
  int rowbase = (ALLT ? t : tl) * 128;
  __fp16* gat = ((__fp16*)gatex) + (size_t)d * dstride;
  int prow = tid >> 4, pseg = tid & 15;
#pragma unroll
  for (int pass = 0; pass < 8; ++pass) {
    int row = pass * 16 + prow;
    uint4 v = *(const uint4*)(&tile[row][pseg * 8]);
    *(uint4*)(gat + ((size_t)(rowbase + row)) * 512 + nb * 128 + pseg * 8) = v;
  }
}

__global__ __launch_bounds__(256, 2) void gemmx_kernel(
    const int* __restrict__ sentT, const float* __restrict__ embed,
    const uint* __restrict__ wihI, const float* __restrict__ biasI,
    uint* __restrict__ gatex, int chunk)
{
  gemmx_body<false>(sentT, embed, nullptr, wihI, biasI, gatex, chunk, blockIdx.x);
}

__global__ __launch_bounds__(256, 2) void gemmx_all_kernel(
    const int* __restrict__ sentT, const uint* __restrict__ embH,
    const uint* __restrict__ wihI, const float* __restrict__ biasI,
    uint* __restrict__ gatex)
{
  gemmx_body<true>(sentT, nullptr, embH, wihI, biasI, gatex,
                   blockIdx.x >> 10, blockIdx.x & 1023);
}

// ---------------------------------------------------------------------------
// LSTM cores.
// ---------------------------------------------------------------------------
struct LstmCtx {
  uint4 wreg[4][4];
  float sl, Ac, Bc;
  int kq, m;
};

__device__ __forceinline__ void lstm_init(LstmCtx& cx, const uint* whh,
                                          int d, int tid)
{
  const float L2E = 1.4426950408889634f;
  cx.kq = tid & 3;
  cx.m = tid >> 2;
  const bool isg = (cx.kq == 2);
  cx.sl = isg ? (2.f * L2E) : (-L2E);
  cx.Ac = isg ? -2.f : 1.f;
  cx.Bc = isg ? 1.f : 0.f;
  const uint4* wh4 = (const uint4*)whh + (size_t)d * 8192;
#pragma unroll
  for (int g = 0; g < 4; ++g) {
    const uint4* row = wh4 + ((size_t)(g * 128 + cx.m)) * 16 + cx.kq * 4;
#pragma unroll
    for (int i = 0; i < 4; ++i) cx.wreg[g][i] = row[i];
  }
}

// Single-pair step (chunked fallback; R15 verified).
__device__ __forceinline__ void lstm_step(
    LstmCtx& cx, __fp16 (*hist)[128], int row_r, int row_w, ushort gxh,
    float& c)
{
  const float L2E = 1.4426950408889634f;
  float a0 = 0.f, a1 = 0.f, a2 = 0.f, a3 = 0.f;
  float b0 = 0.f, b1 = 0.f, b2 = 0.f, b3 = 0.f;
  const uint4* z4 = (const uint4*)(&hist[row_r][cx.kq * 32]);
#pragma unroll
  for (int i = 0; i < 2; ++i) {
    uint4 z = z4[i];
    a0 = fdot2(z.x, cx.wreg[0][i].x, a0);
    a0 = fdot2(z.y, cx.wreg[0][i].y, a0);
    a0 = fdot2(z.z, cx.wreg[0][i].z, a0);
    a0 = fdot2(z.w, cx.wreg[0][i].w, a0);
    a1 = fdot2(z.x, cx.wreg[1][i].x, a1);
    a1 = fdot2(z.y, cx.wreg[1][i].y, a1);
    a1 = fdot2(z.z, cx.wreg[1][i].z, a1);
    a1 = fdot2(z.w, cx.wreg[1][i].w, a1);
    a2 = fdot2(z.x, cx.wreg[2][i].x, a2);
    a2 = fdot2(z.y, cx.wreg[2][i].y, a2);
    a2 = fdot2(z.z, cx.wreg[2][i].z, a2);
    a2 = fdot2(z.w, cx.wreg[2][i].w, a2);
    a3 = fdot2(z.x, cx.wreg[3][i].x, a3);
    a3 = fdot2(z.y, cx.wreg[3][i].y, a3);
    a3 = fdot2(z.z, cx.wreg[3][i].z, a3);
    a3 = fdot2(z.w, cx.wreg[3][i].w, a3);
  }
#pragma unroll
  for (int i = 2; i < 4; ++i) {
    uint4 z = z4[i];
    b0 = fdot2(z.x, cx.wreg[0][i].x, b0);
    b0 = fdot2(z.y, cx.wreg[0][i].y, b0);
    b0 = fdot2(z.z, cx.wreg[0][i].z, b0);
    b0 = fdot2(z.w, cx.wreg[0][i].w, b0);
    b1 = fdot2(z.x, cx.wreg[1][i].x, b1);
    b1 = fdot2(z.y, cx.wreg[1][i].y, b1);
    b1 = fdot2(z.z, cx.wreg[1][i].z, b1);
    b1 = fdot2(z.w, cx.wreg[1][i].w, b1);
    b2 = fdot2(z.x, cx.wreg[2][i].x, b2);
    b2 = fdot2(z.y, cx.wreg[2][i].y, b2);
    b2 = fdot2(z.z, cx.wreg[2][i].z, b2);
    b2 = fdot2(z.w, cx.wreg[2][i].w, b2);
    b3 = fdot2(z.x, cx.wreg[3][i].x, b3);
    b3 = fdot2(z.y, cx.wreg[3][i].y, b3);
    b3 = fdot2(z.z, cx.wreg[3][i].z, b3);
    b3 = fdot2(z.w, cx.wreg[3][i].w, b3);
  }
  a0 += b0; a1 += b1; a2 += b2; a3 += b3;
  a0 = quad_add(a0);
  a1 = quad_add(a1);
  a2 = quad_add(a2);
  a3 = quad_add(a3);
  float s01 = (cx.kq & 1) ? a1 : a0;
  float s23 = (cx.kq & 1) ? a3 : a2;
  float own = (cx.kq & 2) ? s23 : s01;
  own += (float)__builtin_bit_cast(__fp16, gxh);
  float e = fexp2(own * cx.sl);
  float r = frcp(1.f + e);
  float out = cx.Ac * r + cx.Bc;
  float ig = quad_bcast<0x00>(out);
  float fg = quad_bcast<0x55>(out);
  float gg = quad_bcast<0xAA>(out);
  float og = quad_bcast<0xFF>(out);
  c = fg * c + ig * gg;
  float e2 = fexp2(c * (2.f * L2E));
  float r2 = frcp(1.f + e2);
  float th = 1.f - 2.f * r2;
  float hv = og * th;

  if (cx.kq == 0) hist[row_w][cx.m] = (__fp16)hv;
  __builtin_amdgcn_sched_barrier(0);
  asm volatile("s_waitcnt lgkmcnt(0)");
  __builtin_amdgcn_sched_barrier(0);
  __builtin_amdgcn_s_barrier();
}

// Two-pair step (big-ws path). R24: two batch elements per THREAD (same d
// -> same weights). 8 independent 16-deep fdot chains (4 gates x 2 b)
// interleave by ILP in one instruction stream -> the ~900cyc exposed
// serial-chain latency (R15 diagnosis) is filled with real work instead
// of stalling. Issue ~700cyc per step for TWO pairs.
__device__ __forceinline__ void lstm_step2(
    LstmCtx& cx, __fp16 (*histA)[128], __fp16 (*histB)[128],
    int row_r, int row_w, ushort gxa, ushort gxb, float& ca, float& cb)
{
  const float L2E = 1.4426950408889634f;
  float a0 = 0.f, a1 = 0.f, a2 = 0.f, a3 = 0.f;
  float e0 = 0.f, e1 = 0.f, e2 = 0.f, e3 = 0.f;
  const uint4* zA4 = (const uint4*)(&histA[row_r][cx.kq * 32]);
  const uint4* zB4 = (const uint4*)(&histB[row_r][cx.kq * 32]);
#pragma unroll
  for (int i = 0; i < 4; ++i) {
    uint4 zA = zA4[i];
    uint4 zB = zB4[i];
    a0 = fdot2(zA.x, cx.wreg[0][i].x, a0);
    e0 = fdot2(zB.x, cx.wreg[0][i].x, e0);
    a0 = fdot2(zA.y, cx.wreg[0][i].y, a0);
    e0 = fdot2(zB.y, cx.wreg[0][i].y, e0);
    a0 = fdot2(zA.z, cx.wreg[0][i].z, a0);
    e0 = fdot2(zB.z, cx.wreg[0][i].z, e0);
    a0 = fdot2(zA.w, cx.wreg[0][i].w, a0);
    e0 = fdot2(zB.w, cx.wreg[0][i].w, e0);
    a1 = fdot2(zA.x, cx.wreg[1][i].x, a1);
    e1 = fdot2(zB.x, cx.wreg[1][i].x, e1);
    a1 = fdot2(zA.y, cx.wreg[1][i].y, a1);
    e1 = fdot2(zB.y, cx.wreg[1][i].y, e1);
    a1 = fdot2(zA.z, cx.wreg[1][i].z, a1);
    e1 = fdot2(zB.z, cx.wreg[1][i].z, e1);
    a1 = fdot2(zA.w, cx.wreg[1][i].w, a1);
    e1 = fdot2(zB.w, cx.wreg[1][i].w, e1);
    a2 = fdot2(zA.x, cx.wreg[2][i].x, a2);
    e2 = fdot2(zB.x, cx.wreg[2][i].x, e2);
    a2 = fdot2(zA.y, cx.wreg[2][i].y, a2);
    e2 = fdot2(zB.y, cx.wreg[2][i].y, e2);
    a2 = fdot2(zA.z, cx.wreg[2][i].z, a2);
    e2 = fdot2(zB.z, cx.wreg[2][i].z, e2);
    a2 = fdot2(zA.w, cx.wreg[2][i].w, a2);
    e2 = fdot2(zB.w, cx.wreg[2][i].w, e2);
    a3 = fdot2(zA.x, cx.wreg[3][i].x, a3);
    e3 = fdot2(zB.x, cx.wreg[3][i].x, e3);
    a3 = fdot2(zA.y, cx.wreg[3][i].y, a3);
    e3 = fdot2(zB.y, cx.wreg[3][i].y, e3);
    a3 = fdot2(zA.z, cx.wreg[3][i].z, a3);
    e3 = fdot2(zB.z, cx.wreg[3][i].z, e3);
    a3 = fdot2(zA.w, cx.wreg[3][i].w, a3);
    e3 = fdot2(zB.w, cx.wreg[3][i].w, e3);
  }
  a0 = quad_add(a0);
  e0 = quad_add(e0);
  a1 = quad_add(a1);
  e1 = quad_add(e1);
  a2 = quad_add(a2);
  e2 = quad_add(e2);
  a3 = quad_add(a3);
  e3 = quad_add(e3);
  // Pair A nonlinearity (own gate), pair B interleaved.
  float sA01 = (cx.kq & 1) ? a1 : a0;
  float sB01 = (cx.kq & 1) ? e1 : e0;
  float sA23 = (cx.kq & 1) ? a3 : a2;
  float sB23 = (cx.kq & 1) ? e3 : e2;
  float ownA = (cx.kq & 2) ? sA23 : sA01;
  float ownB = (cx.kq & 2) ? sB23 : sB01;
  ownA += (float)__builtin_bit_cast(__fp16, gxa);
  ownB += (float)__builtin_bit_cast(__fp16, gxb);
  float eA = fexp2(ownA * cx.sl);
  float eB = fexp2(ownB * cx.sl);
  float rA = frcp(1.f + eA);
  float rB = frcp(1.f + eB);
  float outA = cx.Ac * rA + cx.Bc;
  float outB = cx.Ac * rB + cx.Bc;
  float igA = quad_bcast<0x00>(outA);
  float igB = quad_bcast<0x00>(outB);
  float fgA = quad_bcast<0x55>(outA);
  float fgB = quad_bcast<0x55>(outB);
  float ggA = quad_bcast<0xAA>(outA);
  float ggB = quad_bcast<0xAA>(outB);
  float ogA = quad_bcast<0xFF>(outA);
  float ogB = quad_bcast<0xFF>(outB);
  ca = fgA * ca + igA * ggA;
  cb = fgB * cb + igB * ggB;
  float e2A = fexp2(ca * (2.f * L2E));
  float e2B = fexp2(cb * (2.f * L2E));
  float r2A = frcp(1.f + e2A);
  float r2B = frcp(1.f + e2B);
  float hvA = ogA * (1.f - 2.f * r2A);
  float hvB = ogB * (1.f - 2.f * r2B);

  if (cx.kq == 0) {
    histA[row_w][cx.m] = (__fp16)hvA;
    histB[row_w][cx.m] = (__fp16)hvB;
  }
  __builtin_amdgcn_sched_barrier(0);
  asm volatile("s_waitcnt lgkmcnt(0)");
  __builtin_amdgcn_sched_barrier(0);
  __builtin_amdgcn_s_barrier();
}

// ---------------------------------------------------------------------------
// Chunked lstm (small-ws fallback; verified).
// ---------------------------------------------------------------------------
__global__ __attribute__((amdgpu_waves_per_eu(2, 2))) __launch_bounds__(512)
void lstm_kernel(
    const uint* __restrict__ gatex, const uint* __restrict__ whh,
    const float* __restrict__ h0, const float* __restrict__ c0,
    float* __restrict__ statec, uint* __restrict__ hh, int chunk)
{
  const int wg = blockIdx.x;
  const int d = wg >> 7, b = wg & 127;
  const int tid = threadIdx.x;

  __shared__ __align__(16) __fp16 hist[128][128];
  LstmCtx cx;
  lstm_init(cx, whh, d, tid);

  float c = (chunk == 0) ? c0[(size_t)(d * 128 + b) * 128 + cx.m]
                         : statec[(size_t)(d * 128 + b) * 128 + cx.m];

  if (tid < 64) {
    uint* h127 = (uint*)&hist[127][0];
    if (chunk == 0) {
      float2 hv = ((const float2*)(h0 + (size_t)(d * 128 + b) * 128))[tid];
      h127[tid] = packh2(hv.x, hv.y);
    } else {
      int sprev = d ? (511 - (chunk * 128 - 1)) : (chunk * 128 - 1);
      h127[tid] = hh[((size_t)(d * 512 + sprev) * 128 + b) * 64 + tid];
    }
  }
  const ushort* gxp = (const ushort*)gatex + (size_t)d * 8388608 +
                      (size_t)b * 512 + 4 * cx.m + cx.kq;

  ushort g0 = gxp[0];
  ushort g1 = gxp[(size_t)1 * 65536];
  ushort g2 = gxp[(size_t)2 * 65536];
  ushort g3 = gxp[(size_t)3 * 65536];
  __syncthreads();

  for (int tl = 0; tl < 128; tl += 4) {
    int i0 = tl + 4 > 127 ? 127 : tl + 4;
    int i1 = tl + 5 > 127 ? 127 : tl + 5;
    int i2 = tl + 6 > 127 ? 127 : tl + 6;
    int i3 = tl + 7 > 127 ? 127 : tl + 7;
    ushort n0 = gxp[(size_t)i0 * 65536];
    ushort n1 = gxp[(size_t)i1 * 65536];
    ushort n2 = gxp[(size_t)i2 * 65536];
    ushort n3 = gxp[(size_t)i3 * 65536];
    lstm_step(cx, hist, (tl + 127) & 127, tl + 0, g0, c);
    lstm_step(cx, hist, (tl + 0) & 127, tl + 1, g1, c);
    lstm_step(cx, hist, (tl + 1) & 127, tl + 2, g2, c);
    lstm_step(cx, hist, (tl + 2) & 127, tl + 3, g3, c);
    g0 = n0; g1 = n1; g2 = n2; g3 = n3;
  }

  if (cx.kq == 0) statec[(size_t)(d * 128 + b) * 128 + cx.m] = c;

  int base = chunk * 128;
  for (int i = tid; i < 2048; i += 512) {
    int sl2 = i >> 4, q4 = i & 15;
    int s = d ? (511 - (base + sl2)) : (base + sl2);
    *(uint4*)(&hh[((size_t)(d * 512 + s) * 128 + b) * 64 + q4 * 4]) =
        *(const uint4*)((const uint*)&hist[sl2][0] + q4 * 4);
  }
}

// ---------------------------------------------------------------------------
// All-timestep lstm — R24 two-batch-per-thread. Grid 128 WGs: wg = d*64 +
// bpair; pairs (b0,b1) = (2*bpair, 2*bpair+1). hist doubles to 64KB.
// ---------------------------------------------------------------------------
__global__ __attribute__((amdgpu_waves_per_eu(2, 2))) __launch_bounds__(512)
void lstm_all_kernel(
    const uint* __restrict__ gatex, const uint* __restrict__ whh,
    const float* __restrict__ h0, const float* __restrict__ c0,
    uint* __restrict__ hh)
{
  const int wg = blockIdx.x;
  const int d = wg >> 6, bpair = wg & 63;
  const int b0 = bpair * 2;
  const int tid = threadIdx.x;

  __shared__ __align__(16) __fp16 hist[2][128][128];   // 64 KB
  LstmCtx cx;
  lstm_init(cx, whh, d, tid);

  float ca = c0[(size_t)(d * 128 + b0) * 128 + cx.m];
  float cb = c0[(size_t)(d * 128 + b0 + 1) * 128 + cx.m];

  if (tid < 128) {
    int p = tid >> 6, t6 = tid & 63;
    uint* h127 = (uint*)&hist[p][127][0];
    float2 hv = ((const float2*)(h0 + (size_t)(d * 128 + b0 + p) * 128))[t6];
    h127[t6] = packh2(hv.x, hv.y);
  }
  const ushort* gxp0 = (const ushort*)gatex + (size_t)d * 33554432 +
                       (size_t)b0 * 512 + 4 * cx.m + cx.kq;
  const ushort* gxp1 = gxp0 + 512;   // b0+1

  ushort ga0 = gxp0[0], gb0 = gxp1[0];
  ushort ga1 = gxp0[(size_t)1 * 65536], gb1 = gxp1[(size_t)1 * 65536];
  ushort ga2 = gxp0[(size_t)2 * 65536], gb2 = gxp1[(size_t)2 * 65536];
  ushort ga3 = gxp0[(size_t)3 * 65536], gb3 = gxp1[(size_t)3 * 65536];
  __syncthreads();

  for (int tl = 0; tl < 512; tl += 4) {
    int i0 = tl + 4 > 511 ? 511 : tl + 4;
    int i1 = tl + 5 > 511 ? 511 : tl + 5;
    int i2 = tl + 6 > 511 ? 511 : tl + 6;
    int i3 = tl + 7 > 511 ? 511 : tl + 7;
    ushort na0 = gxp0[(size_t)i0 * 65536], nb0 = gxp1[(size_t)i0 * 65536];
    ushort na1 = gxp0[(size_t)i1 * 65536], nb1 = gxp1[(size_t)i1 * 65536];
    ushort na2 = gxp0[(size_t)i2 * 65536], nb2 = gxp1[(size_t)i2 * 65536];
    ushort na3 = gxp0[(size_t)i3 * 65536], nb3 = gxp1[(size_t)i3 * 65536];
    lstm_step2(cx, hist[0], hist[1], (tl + 127) & 127, (tl + 0) & 127, ga0, gb0, ca, cb);
    lstm_step2(cx, hist[0], hist[1], (tl + 0) & 127, (tl + 1) & 127, ga1, gb1, ca, cb);
    lstm_step2(cx, hist[0], hist[1], (tl + 1) & 127, (tl + 2) & 127, ga2, gb2, ca, cb);
    lstm_step2(cx, hist[0], hist[1], (tl + 2) & 127, (tl + 3) & 127, ga3, gb3, ca, cb);
    ga0 = na0; ga1 = na1; ga2 = na2; ga3 = na3;
    gb0 = nb0; gb1 = nb1; gb2 = nb2; gb3 = nb3;

    if (((tl + 3) & 127) == 127) {
      int base = ((tl + 3) >> 7) * 128;
      for (int i = tid; i < 4096; i += 512) {
        int p2 = i >> 11, r2i = i & 2047;
        int sl2 = r2i >> 4, q4 = r2i & 15;
        int s = d ? (511 - (base + sl2)) : (base + sl2);
        *(uint4*)(&hh[((size_t)(d * 512 + s) * 128 + (b0 + p2)) * 64 + q4 * 4]) =
            *(const uint4*)((const uint*)&hist[p2][sl2][0] + q4 * 4);
      }
      __syncthreads();
    }
  }
}

// ---------------------------------------------------------------------------
// Output projection — MFMA GEMM, zero LDS (verified).
// ---------------------------------------------------------------------------
__global__ __launch_bounds__(256) void outproj_kernel(
    const uint* __restrict__ hh, const uint* __restrict__ woutp,
    const float* __restrict__ bout, float* __restrict__ feats)
{
  int tid = threadIdx.x;
  int w = tid >> 6, lane = tid & 63;
  int q = lane >> 4, c = lane & 15;
  int row0 = blockIdx.x * 64 + w * 16;

  const uint4* wp4 = (const uint4*)woutp;
  uint4 bf0[8], bf1[8];
#pragma unroll
  for (int ks = 0; ks < 8; ++ks) {
    bf0[ks] = wp4[(size_t)c * 32 + ks * 4 + q];
    bf1[ks] = wp4[(size_t)(16 + c) * 32 + ks * 4 + q];
  }

  int rr = row0 + c;
  int br = rr >> 9, sr = rr & 511;
  const uint4* af4 = (const uint4*)(hh + ((size_t)(sr * BATCH + br)) * 64);
  const uint4* ab4 = (const uint4*)(hh + ((size_t)((SEQ + sr) * BATCH + br)) * 64);

  floatx4 acc0 = (floatx4){0.f, 0.f, 0.f, 0.f};
  floatx4 acc1 = (floatx4){0.f, 0.f, 0.f, 0.f};
#pragma unroll
  for (int ks = 0; ks < 8; ++ks) {
    uint4 a = (ks < 4) ? af4[ks * 4 + q] : ab4[(ks - 4) * 4 + q];
    half8_t af = __builtin_bit_cast(half8_t, a);
    acc0 = __builtin_amdgcn_mfma_f32_16x16x32_f16(
        af, __builtin_bit_cast(half8_t, bf0[ks]), acc0, 0, 0, 0);
    acc1 = __builtin_amdgcn_mfma_f32_16x16x32_f16(
        af, __builtin_bit_cast(half8_t, bf1[ks]), acc1, 0, 0, 0);
  }

  float bb0 = bout[c], bb1 = bout[16 + c];
#pragma unroll
  for (int reg = 0; reg < 4; ++reg) {
    int orow = row0 + q * 4 + reg;
    feats[(size_t)orow * 32 + c] = acc0[reg] + bb0;
    feats[(size_t)orow * 32 + 16 + c] = acc1[reg] + bb1;
  }
}

// ---------------------------------------------------------------------------
// CRF stage A (verified)
// ---------------------------------------------------------------------------
__global__ __launch_bounds__(64) void crf_seg_kernel(
    const float* __restrict__ feats, const float* __restrict__ trans,
    uint* __restrict__ segP, float* __restrict__ segL)
{
  const float L2E = 1.4426950408889634f;
  int blk = blockIdx.x;
  int b = blk >> 5, j = blk & 31;
  int tstart = 1 + 16 * j;
  int nsteps = (j == 31) ? 15 : 16;
  int lane = threadIdx.x;
  int c = lane & 15, q = lane >> 4;

  half8_t afr[2];
#pragma unroll
  for (int rt = 0; rt < 2; ++rt) {
    const float* trow = trans + (rt * 16 + c) * 32 + q * 8;
    float e[8];
#pragma unroll
    for (int i = 0; i < 8; ++i) e[i] = fexp2(trow[i] * L2E);
    uint4 u;
    u.x = packh2(e[0], e[1]); u.y = packh2(e[2], e[3]);
    u.z = packh2(e[4], e[5]); u.w = packh2(e[6], e[7]);
    afr[rt] = __builtin_bit_cast(half8_t, u);
  }
  half8_t bfr[2];
#pragma unroll
  for (int ct = 0; ct < 2; ++ct) {
    uint4 u;
    uint vals[8];
#pragma unroll
    for (int i = 0; i < 8; ++i)
      vals[i] = ((q * 8 + i) == (ct * 16 + c)) ? 0x3C00u : 0u;
    u.x = vals[0] | (vals[1] << 16);
    u.y = vals[2] | (vals[3] << 16);
    u.z = vals[4] | (vals[5] << 16);
    u.w = vals[6] | (vals[7] << 16);
    bfr[ct] = __builtin_bit_cast(half8_t, u);
  }

  __shared__ __fp16 P16[32 * 36];

  const float* fb = feats + ((size_t)b * SEQ + tstart) * NTAG;
  float Lacc = 0.f;
  float4 pre0 = *(const float4*)(fb + q * 4);
  float4 pre1 = *(const float4*)(fb + 16 + q * 4);

  for (int s = 0; s < nsteps; ++s) {
    float4 f0 = pre0, f1 = pre1;
    if (s + 1 < nsteps) {
      pre0 = *(const float4*)(fb + (s + 1) * 32 + q * 4);
      pre1 = *(const float4*)(fb + (s + 1) * 32 + 16 + q * 4);
    }
    floatx4 z4 = (floatx4){0.f, 0.f, 0.f, 0.f};
    floatx4 c00 = __builtin_amdgcn_mfma_f32_16x16x32_f16(afr[0], bfr[0], z4, 0, 0, 0);
    floatx4 c01 = __builtin_amdgcn_mfma_f32_16x16x32_f16(afr[0], bfr[1], z4, 0, 0, 0);
    floatx4 c10 = __builtin_amdgcn_mfma_f32_16x16x32_f16(afr[1], bfr[0], z4, 0, 0, 0);
    floatx4 c11 = __builtin_amdgcn_mfma_f32_16x16x32_f16(afr[1], bfr[1], z4, 0, 0, 0);
    float pf0[4], pf1[4];
    pf0[0] = fexp2(f0.x * L2E); pf0[1] = fexp2(f0.y * L2E);
    pf0[2] = fexp2(f0.z * L2E); pf0[3] = fexp2(f0.w * L2E);
    pf1[0] = fexp2(f1.x * L2E); pf1[1] = fexp2(f1.y * L2E);
    pf1[2] = fexp2(f1.z * L2E); pf1[3] = fexp2(f1.w * L2E);
    float v00[4], v01[4], v10[4], v11[4];
#pragma unroll
    for (int rg = 0; rg < 4; ++rg) {
      v00[rg] = c00[rg] * pf0[rg];
      v01[rg] = c01[rg] * pf0[rg];
      v10[rg] = c10[rg] * pf1[rg];
      v11[rg] = c11[rg] * pf1[rg];
    }
    float mx = 0.f;
#pragma unroll
    for (int rg = 0; rg < 4; ++rg)
      mx = fmaxf(mx, fmaxf(fmaxf(v00[rg], v01[rg]), fmaxf(v10[rg], v11[rg])));
    uint ub = (uint)__builtin_amdgcn_readfirstlane((int)__builtin_bit_cast(uint, mx));
    int e = (int)((ub >> 23) & 255u);
    Lacc += (float)(e - 127);
    float sc = __builtin_bit_cast(float, (uint)((254 - e) << 23));

    __syncthreads();
    {
      uint2 wv2;
      wv2.x = packh2(v00[0] * sc, v00[1] * sc);
      wv2.y = packh2(v00[2] * sc, v00[3] * sc);
      *(uint2*)(&P16[c * 36 + q * 4]) = wv2;
      wv2.x = packh2(v10[0] * sc, v10[1] * sc);
      wv2.y = packh2(v10[2] * sc, v10[3] * sc);
      *(uint2*)(&P16[c * 36 + 16 + q * 4]) = wv2;
      wv2.x = packh2(v01[0] * sc, v01[1] * sc);
      wv2.y = packh2(v01[2] * sc, v01[3] * sc);
      *(uint2*)(&P16[(16 + c) * 36 + q * 4]) = wv2;
      wv2.x = packh2(v11[0] * sc, v11[1] * sc);
      wv2.y = packh2(v11[2] * sc, v11[3] * sc);
      *(uint2*)(&P16[(16 + c) * 36 + 16 + q * 4]) = wv2;
    }
    __syncthreads();
    {
      uint2 lo0 = *(const uint2*)(&P16[c * 36 + q * 8]);
      uint2 hi0 = *(const uint2*)(&P16[c * 36 + q * 8 + 4]);
      uint4 u0; u0.x = lo0.x; u0.y = lo0.y; u0.z = hi0.x; u0.w = hi0.y;
      bfr[0] = __builtin_bit_cast(half8_t, u0);
      uint2 lo1 = *(const uint2*)(&P16[(16 + c) * 36 + q * 8]);
      uint2 hi1 = *(const uint2*)(&P16[(16 + c) * 36 + q * 8 + 4]);
      uint4 u1; u1.x = lo1.x; u1.y = lo1.y; u1.z = hi1.x; u1.w = hi1.y;
      bfr[1] = __builtin_bit_cast(half8_t, u1);
    }
  }
  __syncthreads();
  uint* gp = segP + (size_t)blk * 512;
  if (lane < 32) {
    int i = lane;
#pragma unroll
    for (int tp = 0; tp < 16; ++tp) {
      uint lo = (uint)__builtin_bit_cast(unsigned short, P16[(2 * tp) * 36 + i]);
      uint hi = (uint)__builtin_bit_cast(unsigned short, P16[(2 * tp + 1) * 36 + i]);
      gp[i * 16 + tp] = lo | (hi << 16);
    }
  }
  if (lane == 0) segL[blk] = Lacc;
}

// ---------------------------------------------------------------------------
// CRF stage B + numerator merged (verified)
// ---------------------------------------------------------------------------
__global__ __launch_bounds__(64) void crf_comb_kernel(
    const int* __restrict__ tags, const float* __restrict__ feats,
    const float* __restrict__ trans, const uint* __restrict__ segP,
    const float* __restrict__ segL, float* __restrict__ num,
    float* __restrict__ den)
{
  const float L2E = 1.4426950408889634f, LN2 = 0.6931471805599453f;
  int b = blockIdx.x, l = threadIdx.x;

  {
    const int* tb = tags + b * SEQ;
    float acc = 0.f;
    for (int s = l; s < SEQ; s += 64) {
      int tg = tb[s];
      int pv = (s == 0) ? START_TAG : tb[s - 1];
      acc += trans[pv * NTAG + tg] + feats[((size_t)b * SEQ + s) * NTAG + tg];
    }
#pragma unroll
    for (int msk = 1; msk < 64; msk <<= 1) acc += __shfl_xor(acc, msk);
    if (l == 0) num[b] = acc + trans[tb[SEQ - 1] * NTAG + END_TAG];
  }

  int i = l & 31, hp = l >> 5;
  const float* fb = feats + (size_t)b * SEQ * NTAG;

  float sT = 0.f;
  for (int p = 0; p < 32; ++p) sT += fexp2(trans[i * 32 + p] * L2E);
  float v = (1.f + sT) * fexp2(fb[i] * L2E);
  float L = -10000.f * L2E;

  float vo = __shfl_xor(v, 1);
  uint pv = (i & 1) ? packh2(vo, v) : packh2(v, vo);

  const uint* gp0 = segP + (size_t)b * 32 * 512 + i * 16 + hp * 8;
  uint4 ra = *(const uint4*)(gp0);
  uint4 rb = *(const uint4*)(gp0 + 4);

  for (int seg = 0; seg < 32; ++seg) {
    uint4 ca = ra, cb = rb;
    if (seg + 1 < 32) {
      ra = *(const uint4*)(gp0 + (seg + 1) * 512);
      rb = *(const uint4*)(gp0 + (seg + 1) * 512 + 4);
    }
    float g0 = __shfl(__builtin_bit_cast(float, pv), hp * 16 + 0);
    float g1 = __shfl(__builtin_bit_cast(float, pv), hp * 16 + 2);
    float g2 = __shfl(__builtin_bit_cast(float, pv), hp * 16 + 4);
    float g3 = __shfl(__builtin_bit_cast(float, pv), hp * 16 + 6);
    float g4 = __shfl(__builtin_bit_cast(float, pv), hp * 16 + 8);
    float g5 = __shfl(__builtin_bit_cast(float, pv), hp * 16 + 10);
    float g6 = __shfl(__builtin_bit_cast(float, pv), hp * 16 + 12);
    float g7 = __shfl(__builtin_bit_cast(float, pv), hp * 16 + 14);
    float acc = 0.f;
    acc = fdot2(__builtin_bit_cast(uint, g0), ca.x, acc);
    acc = fdot2(__builtin_bit_cast(uint, g1), ca.y, acc);
    acc = fdot2(__builtin_bit_cast(uint, g2), ca.z, acc);
    acc = fdot2(__builtin_bit_cast(uint, g3), ca.w, acc);
    acc = fdot2(__builtin_bit_cast(uint, g4), cb.x, acc);
    acc = fdot2(__builtin_bit_cast(uint, g5), cb.y, acc);
    acc = fdot2(__builtin_bit_cast(uint, g6), cb.z, acc);
    acc = fdot2(__builtin_bit_cast(uint, g7), cb.w, acc);
    float sm = acc + __shfl_xor(acc, 32);
    uint ub = (uint)__builtin_amdgcn_readfirstlane((int)__builtin_bit_cast(uint, sm));
    int e = (int)((ub >> 23) & 255u);
    L += (float)(e - 127) + segL[b * 32 + seg];
    float sc = __builtin_bit_cast(float, (uint)((254 - e) << 23));
    v = sm * sc;
    float vo2 = __shfl_xor(v, 1);
    pv = (i & 1) ? packh2(vo2, v) : packh2(v, vo2);
  }
  float wv = v * fexp2(trans[i * 32 + END_TAG] * L2E);
#pragma unroll
  for (int msk = 1; msk <= 16; msk <<= 1) wv += __shfl_xor(wv, msk);
  if (l == 0) den[b] = (L + flog2(wv)) * LN2;
}

__global__ __launch_bounds__(128) void final_kernel(
    const float* __restrict__ num, const float* __restrict__ den,
    float* __restrict__ out)
{
  int tid = threadIdx.x;
  float v = num[tid] - den[tid];
#pragma unroll
  for (int msk = 1; msk < 64; msk <<= 1) v += __shfl_xor(v, msk);
  __shared__ float tmp[2];
  if ((tid & 63) == 0) tmp[tid >> 6] = v;
  __syncthreads();
  if (tid == 0) out[0] = (tmp[0] + tmp[1]) * (1.f / 128.f);
}

// ---------------------------------------------------------------------------
// Workspace layouts (same as R23).
// ---------------------------------------------------------------------------
extern "C" void kernel_launch(void* const* d_in, const int* in_sizes, int n_in,
                              void* d_out, int out_size, void* d_ws, size_t ws_size,
                              hipStream_t stream)
{
  const int* sentence = (const int*)d_in[0];
  const int* tags = (const int*)d_in[1];
  const float* embed = (const float*)d_in[2];
  const float* Wihf = (const float*)d_in[3];
  const float* Whhf = (const float*)d_in[4];
  const float* bihf = (const float*)d_in[5];
  const float* bhhf = (const float*)d_in[6];
  const float* Wihb = (const float*)d_in[7];
  const float* Whhb = (const float*)d_in[8];
  const float* bihb = (const float*)d_in[9];
  const float* bhhb = (const float*)d_in[10];
  const float* Wout = (const float*)d_in[11];
  const float* bout = (const float*)d_in[12];
  const float* trans = (const float*)d_in[13];
  const float* h0 = (const float*)d_in[14];
  const float* c0 = (const float*)d_in[15];
  float* out = (float*)d_out;

  char* ws = (char*)d_ws;
  uint* wihI = (uint*)(ws + 0);
  uint* whh = (uint*)(ws + 262144);
  uint* woutp = (uint*)(ws + 524288);
  float* biasI = (float*)(ws + 540672);
  float* numb = (float*)(ws + 544768);
  float* denb = (float*)(ws + 545280);
  float* statec = (float*)(ws + 545792);
  int* sentT = (int*)(ws + 700416);
  uint* hh = (uint*)(ws + 1048576);
  uint* embH = (uint*)(ws + 1048576);   // overlays hh; dead before lstm
  uint* gatex = (uint*)(ws + 34603008);
  float* feats = (float*)(ws + 34603008);
  uint* segP = (uint*)(ws + 42991616);
  float* segL = (float*)(ws + 51380224);

  hipLaunchKernelGGL(prep_kernel, dim3(8980), dim3(256), 0, stream,
                     Wihf, Whhf, bihf, bhhf, Wihb, Whhb, bihb, bhhb, Wout,
                     sentence, embed, wihI, whh, woutp, biasI, sentT, embH);

  bool big = ws_size >= 168820736ull;
  if (big) {
    hipLaunchKernelGGL(gemmx_all_kernel, dim3(4096), dim3(256), 0, stream,
                       sentT, embH, wihI, biasI, gatex);
    hipLaunchKernelGGL(lstm_all_kernel, dim3(128), dim3(512), 0, stream,
                       gatex, whh, h0, c0, hh);
  } else {
    for (int c = 0; c < 4; ++c) {
      hipLaunchKernelGGL(gemmx_kernel, dim3(1024), dim3(256), 0, stream,
                         sentT, embed, wihI, biasI, gatex, c);
      hipLaunchKernelGGL(lstm_kernel, dim3(256), dim3(512), 0, stream,
                         gatex, whh, h0, c0, statec, hh, c);
    }
  }

  hipLaunchKernelGGL(outproj_kernel, dim3(1024), dim3(256), 0, stream,
                     hh, woutp, bout, feats);
  hipLaunchKernelGGL(crf_seg_kernel, dim3(4096), dim3(64), 0, stream,
                     feats, trans, segP, segL);
  hipLaunchKernelGGL(crf_comb_kernel, dim3(128), dim3(64), 0, stream,
                     tags, feats, trans, segP, segL, numb, denb);
  hipLaunchKernelGGL(final_kernel, dim3(1), dim3(128), 0, stream,
                     numb, denb, out);
}

// Round 17
// 483.498 us; speedup vs baseline: 1.3758x; 1.3758x over previous
//
#include <hip/hip_runtime.h>

typedef unsigned int uint;
typedef unsigned short ushort;
typedef __fp16 half2_t __attribute__((ext_vector_type(2)));
typedef __fp16 half8_t __attribute__((ext_vector_type(8)));
typedef float floatx4 __attribute__((ext_vector_type(4)));

#define SEQ 512
#define BATCH 128
#define HID 128
#define NTAG 32
#define START_TAG 30
#define END_TAG 31

__device__ __forceinline__ float fdot2(uint a, uint b, float c) {
  return __builtin_amdgcn_fdot2(__builtin_bit_cast(half2_t, a),
                                __builtin_bit_cast(half2_t, b), c, false);
}
__device__ __forceinline__ uint packh2(float a, float b) {
  half2_t h = __builtin_amdgcn_cvt_pkrtz(a, b);
  return __builtin_bit_cast(uint, h);
}
__device__ __forceinline__ float frcp(float x) { return __builtin_amdgcn_rcpf(x); }
__device__ __forceinline__ float fexp2(float x) { return __builtin_amdgcn_exp2f(x); }
__device__ __forceinline__ float flog2(float x) { return __builtin_amdgcn_logf(x); }

// Quad butterfly sum via DPP quad_perm (VALU pipe, no LDS).
__device__ __forceinline__ float quad_add(float x) {
  int a = __builtin_bit_cast(int, x);
  int b = __builtin_amdgcn_update_dpp(0, a, 0xB1, 0xF, 0xF, true);
  float y = x + __builtin_bit_cast(float, b);
  int c2 = __builtin_bit_cast(int, y);
  int d2 = __builtin_amdgcn_update_dpp(0, c2, 0x4E, 0xF, 0xF, true);
  return y + __builtin_bit_cast(float, d2);
}
template <int CTRL>
__device__ __forceinline__ float quad_bcast(float x) {
  int a = __builtin_bit_cast(int, x);
  int b = __builtin_amdgcn_update_dpp(0, a, CTRL, 0xF, 0xF, true);
  return __builtin_bit_cast(float, b);
}

// ---------------------------------------------------------------------------
// prep (R23: + sentT transpose + embed fp32->fp16)
// ---------------------------------------------------------------------------
__global__ __launch_bounds__(256) void prep_kernel(
    const float* __restrict__ Wihf, const float* __restrict__ Whhf,
    const float* __restrict__ bihf, const float* __restrict__ bhhf,
    const float* __restrict__ Wihb, const float* __restrict__ Whhb,
    const float* __restrict__ bihb, const float* __restrict__ bhhb,
    const float* __restrict__ Wout, const int* __restrict__ sentence,
    const float* __restrict__ embed,
    uint* __restrict__ wihI, uint* __restrict__ whh,
    uint* __restrict__ woutp, float* __restrict__ biasI,
    int* __restrict__ sentT, uint* __restrict__ embH)
{
  int idx = blockIdx.x * 256 + threadIdx.x;
  if (idx < 65536) {
    int d = idx >> 15, rem = idx & 32767;
    int n = rem >> 6, dw = rem & 63;
    int m = n >> 2, q = n & 3;
    int g = q * 128 + m;
    const float* W = d ? Wihb : Wihf;
    wihI[idx] = packh2(W[g * 128 + 2 * dw], W[g * 128 + 2 * dw + 1]);
  }
  int i2 = idx - 65536;
  if (i2 >= 0 && i2 < 65536) {
    int d = i2 >> 15, rem = i2 & 32767;
    int g = rem >> 6, dw = rem & 63;
    const float* W = d ? Whhb : Whhf;
    whh[i2] = packh2(W[g * 128 + 2 * dw], W[g * 128 + 2 * dw + 1]);
  }
  int i3 = idx - 131072;
  if (i3 >= 0 && i3 < 4096) {
    int k = i3 >> 7, dw = i3 & 127;
    float a, b2;
    if (dw < 64) { a = Wout[k * 256 + 2 * dw]; b2 = Wout[k * 256 + 2 * dw + 1]; }
    else { int j = dw - 64; a = Wout[k * 256 + 128 + 2 * j]; b2 = Wout[k * 256 + 128 + 2 * j + 1]; }
    woutp[i3] = packh2(a, b2);
  }
  int i4 = idx - 135168;
  if (i4 >= 0 && i4 < 1024) {
    int d = i4 >> 9, n = i4 & 511;
    int g = (n & 3) * 128 + (n >> 2);
    biasI[i4] = d ? (bihb[g] + bhhb[g]) : (bihf[g] + bhhf[g]);
  }
  int i5 = idx - 136192;
  if (i5 >= 0 && i5 < 65536) {
    int b = i5 & 127, s = i5 >> 7;
    sentT[i5] = sentence[b * SEQ + s];
  }
  int i6 = idx - 201728;
  if (i6 >= 0 && i6 < 2097152) {
    embH[i6] = packh2(embed[2 * i6], embed[2 * i6 + 1]);
  }
}

// ---------------------------------------------------------------------------
// gemmx core (R22 LDS-staged output; R23 fp16 embed on the ALLT path).
// ---------------------------------------------------------------------------
template <bool ALLT>
__device__ __forceinline__ void gemmx_body(
    const int* __restrict__ sentT, const float* __restrict__ embed,
    const uint* __restrict__ embH,
    const uint* __restrict__ wihI, const float* __restrict__ biasI,
    uint* __restrict__ gatex, int chunk, int blk)
{
  int tl = blk & 127, nb = (blk >> 7) & 3, d = blk >> 9;
  int t = chunk * 128 + tl;
  int s = d ? (511 - t) : t;
  __shared__ int tok[128];
  __shared__ __align__(16) __fp16 tile[128][136];
  int tid = threadIdx.x;
  if (tid < 128) tok[tid] = sentT[s * 128 + tid];
  __syncthreads();

  int w = tid >> 6, lane = tid & 63;
  int q = lane >> 4, r = lane & 15;
  int wr = w >> 1, wc = w & 1;
  int r0 = wr * 64;
  int cl0 = wc * 64;
  int c0 = nb * 128 + cl0;

  floatx4 acc[4][4];
#pragma unroll
  for (int i = 0; i < 4; ++i)
#pragma unroll
    for (int j = 0; j < 4; ++j) acc[i][j] = (floatx4){0.f, 0.f, 0.f, 0.f};

  const uint4* bptr[4];
#pragma unroll
  for (int j = 0; j < 4; ++j)
    bptr[j] = (const uint4*)(wihI + ((size_t)d * 512 + c0 + j * 16 + r) * 64) + q;

  if constexpr (ALLT) {
    const uint4* aptr[4];
#pragma unroll
    for (int i = 0; i < 4; ++i)
      aptr[i] = (const uint4*)embH + (size_t)tok[r0 + i * 16 + r] * 16 + q;
#pragma unroll
    for (int kc = 0; kc < 4; ++kc) {
      half8_t af[4], bf[4];
#pragma unroll
      for (int i = 0; i < 4; ++i)
        af[i] = __builtin_bit_cast(half8_t, aptr[i][kc * 4]);
#pragma unroll
      for (int j = 0; j < 4; ++j)
        bf[j] = __builtin_bit_cast(half8_t, bptr[j][kc * 4]);
#pragma unroll
      for (int i = 0; i < 4; ++i)
#pragma unroll
        for (int j = 0; j < 4; ++j)
          acc[i][j] = __builtin_amdgcn_mfma_f32_16x16x32_f16(af[i], bf[j], acc[i][j], 0, 0, 0);
    }
  } else {
    const float4* aptr[4];
#pragma unroll
    for (int i = 0; i < 4; ++i)
      aptr[i] = (const float4*)(embed + (size_t)tok[r0 + i * 16 + r] * HID) + q * 2;
#pragma unroll
    for (int kc = 0; kc < 4; ++kc) {
      half8_t af[4], bf[4];
#pragma unroll
      for (int i = 0; i < 4; ++i) {
        float4 x0 = aptr[i][kc * 8];
        float4 x1 = aptr[i][kc * 8 + 1];
        uint4 u;
        u.x = packh2(x0.x, x0.y); u.y = packh2(x0.z, x0.w);
        u.z = packh2(x1.x, x1.y); u.w = packh2(x1.z, x1.w);
        af[i] = __builtin_bit_cast(half8_t, u);
      }
#pragma unroll
      for (int j = 0; j < 4; ++j)
        bf[j] = __builtin_bit_cast(half8_t, bptr[j][kc * 4]);
#pragma unroll
      for (int i = 0; i < 4; ++i)
#pragma unroll
        for (int j = 0; j < 4; ++j)
          acc[i][j] = __builtin_amdgcn_mfma_f32_16x16x32_f16(af[i], bf[j], acc[i][j], 0, 0, 0);
    }
  }

#pragma unroll
  for (int j = 0; j < 4; ++j) {
    int cl = cl0 + j * 16 + r;
    float bb = biasI[d * 512 + nb * 128 + cl];
#pragma unroll
    for (int i = 0; i < 4; ++i) {
      int rb = r0 + i * 16 + q * 4;
#pragma unroll
      for (int reg = 0; reg < 4; ++reg)
        tile[rb + reg][cl] = (__fp16)(acc[i][j][reg] + bb);
    }
  }
  __syncthreads();

  size_t dstride = ALLT ? (size_t)65536 * 512 : (size_t)16384 * 512;
  int rowbase = (ALLT ? t : tl) * 128;
  __fp16* gat = ((__fp16*)gatex) + (size_t)d * dstride;
  int prow = tid >> 4, pseg = tid & 15;
#pragma unroll
  for (int pass = 0; pass < 8; ++pass) {
    int row = pass * 16 + prow;
    uint4 v = *(const uint4*)(&tile[row][pseg * 8]);
    *(uint4*)(gat + ((size_t)(rowbase + row)) * 512 + nb * 128 + pseg * 8) = v;
  }
}

__global__ __launch_bounds__(256, 2) void gemmx_kernel(
    const int* __restrict__ sentT, const float* __restrict__ embed,
    const uint* __restrict__ wihI, const float* __restrict__ biasI,
    uint* __restrict__ gatex, int chunk)
{
  gemmx_body<false>(sentT, embed, nullptr, wihI, biasI, gatex, chunk, blockIdx.x);
}

__global__ __launch_bounds__(256, 2) void gemmx_all_kernel(
    const int* __restrict__ sentT, const uint* __restrict__ embH,
    const uint* __restrict__ wihI, const float* __restrict__ biasI,
    uint* __restrict__ gatex)
{
  gemmx_body<true>(sentT, nullptr, embH, wihI, biasI, gatex,
                   blockIdx.x >> 10, blockIdx.x & 1023);
}

// ---------------------------------------------------------------------------
// LSTM step core (R15 structure; verified).
// ---------------------------------------------------------------------------
struct LstmCtx {
  uint4 wreg[4][4];
  float sl, Ac, Bc;
  int kq, m;
};

__device__ __forceinline__ void lstm_step(
    LstmCtx& cx, __fp16 (*hist)[128], int row_r, int row_w, ushort gxh,
    float& c)
{
  const float L2E = 1.4426950408889634f;
  float a0 = 0.f, a1 = 0.f, a2 = 0.f, a3 = 0.f;
  float b0 = 0.f, b1 = 0.f, b2 = 0.f, b3 = 0.f;
  const uint4* z4 = (const uint4*)(&hist[row_r][cx.kq * 32]);
#pragma unroll
  for (int i = 0; i < 2; ++i) {
    uint4 z = z4[i];
    a0 = fdot2(z.x, cx.wreg[0][i].x, a0);
    a0 = fdot2(z.y, cx.wreg[0][i].y, a0);
    a0 = fdot2(z.z, cx.wreg[0][i].z, a0);
    a0 = fdot2(z.w, cx.wreg[0][i].w, a0);
    a1 = fdot2(z.x, cx.wreg[1][i].x, a1);
    a1 = fdot2(z.y, cx.wreg[1][i].y, a1);
    a1 = fdot2(z.z, cx.wreg[1][i].z, a1);
    a1 = fdot2(z.w, cx.wreg[1][i].w, a1);
    a2 = fdot2(z.x, cx.wreg[2][i].x, a2);
    a2 = fdot2(z.y, cx.wreg[2][i].y, a2);
    a2 = fdot2(z.z, cx.wreg[2][i].z, a2);
    a2 = fdot2(z.w, cx.wreg[2][i].w, a2);
    a3 = fdot2(z.x, cx.wreg[3][i].x, a3);
    a3 = fdot2(z.y, cx.wreg[3][i].y, a3);
    a3 = fdot2(z.z, cx.wreg[3][i].z, a3);
    a3 = fdot2(z.w, cx.wreg[3][i].w, a3);
  }
#pragma unroll
  for (int i = 2; i < 4; ++i) {
    uint4 z = z4[i];
    b0 = fdot2(z.x, cx.wreg[0][i].x, b0);
    b0 = fdot2(z.y, cx.wreg[0][i].y, b0);
    b0 = fdot2(z.z, cx.wreg[0][i].z, b0);
    b0 = fdot2(z.w, cx.wreg[0][i].w, b0);
    b1 = fdot2(z.x, cx.wreg[1][i].x, b1);
    b1 = fdot2(z.y, cx.wreg[1][i].y, b1);
    b1 = fdot2(z.z, cx.wreg[1][i].z, b1);
    b1 = fdot2(z.w, cx.wreg[1][i].w, b1);
    b2 = fdot2(z.x, cx.wreg[2][i].x, b2);
    b2 = fdot2(z.y, cx.wreg[2][i].y, b2);
    b2 = fdot2(z.z, cx.wreg[2][i].z, b2);
    b2 = fdot2(z.w, cx.wreg[2][i].w, b2);
    b3 = fdot2(z.x, cx.wreg[3][i].x, b3);
    b3 = fdot2(z.y, cx.wreg[3][i].y, b3);
    b3 = fdot2(z.z, cx.wreg[3][i].z, b3);
    b3 = fdot2(z.w, cx.wreg[3][i].w, b3);
  }
  a0 += b0; a1 += b1; a2 += b2; a3 += b3;
  a0 = quad_add(a0);
  a1 = quad_add(a1);
  a2 = quad_add(a2);
  a3 = quad_add(a3);
  float s01 = (cx.kq & 1) ? a1 : a0;
  float s23 = (cx.kq & 1) ? a3 : a2;
  float own = (cx.kq & 2) ? s23 : s01;
  own += (float)__builtin_bit_cast(__fp16, gxh);
  float e = fexp2(own * cx.sl);
  float r = frcp(1.f + e);
  float out = cx.Ac * r + cx.Bc;
  float ig = quad_bcast<0x00>(out);
  float fg = quad_bcast<0x55>(out);
  float gg = quad_bcast<0xAA>(out);
  float og = quad_bcast<0xFF>(out);
  c = fg * c + ig * gg;
  float e2 = fexp2(c * (2.f * L2E));
  float r2 = frcp(1.f + e2);
  float th = 1.f - 2.f * r2;
  float hv = og * th;

  if (cx.kq == 0) hist[row_w][cx.m] = (__fp16)hv;
  __builtin_amdgcn_sched_barrier(0);
  asm volatile("s_waitcnt lgkmcnt(0)");
  __builtin_amdgcn_sched_barrier(0);
  __builtin_amdgcn_s_barrier();
}

__device__ __forceinline__ void lstm_init(LstmCtx& cx, const uint* whh,
                                          int d, int tid)
{
  const float L2E = 1.4426950408889634f;
  cx.kq = tid & 3;
  cx.m = tid >> 2;
  const bool isg = (cx.kq == 2);
  cx.sl = isg ? (2.f * L2E) : (-L2E);
  cx.Ac = isg ? -2.f : 1.f;
  cx.Bc = isg ? 1.f : 0.f;
  const uint4* wh4 = (const uint4*)whh + (size_t)d * 8192;
#pragma unroll
  for (int g = 0; g < 4; ++g) {
    const uint4* row = wh4 + ((size_t)(g * 128 + cx.m)) * 16 + cx.kq * 4;
#pragma unroll
    for (int i = 0; i < 4; ++i) cx.wreg[g][i] = row[i];
  }
}

// ---------------------------------------------------------------------------
// Chunked lstm (small-ws fallback).
// ---------------------------------------------------------------------------
__global__ __attribute__((amdgpu_waves_per_eu(2, 2))) __launch_bounds__(512)
void lstm_kernel(
    const uint* __restrict__ gatex, const uint* __restrict__ whh,
    const float* __restrict__ h0, const float* __restrict__ c0,
    float* __restrict__ statec, uint* __restrict__ hh, int chunk)
{
  const int wg = blockIdx.x;
  const int d = wg >> 7, b = wg & 127;
  const int tid = threadIdx.x;

  __shared__ __align__(16) __fp16 hist[128][128];
  LstmCtx cx;
  lstm_init(cx, whh, d, tid);

  float c = (chunk == 0) ? c0[(size_t)(d * 128 + b) * 128 + cx.m]
                         : statec[(size_t)(d * 128 + b) * 128 + cx.m];

  if (tid < 64) {
    uint* h127 = (uint*)&hist[127][0];
    if (chunk == 0) {
      float2 hv = ((const float2*)(h0 + (size_t)(d * 128 + b) * 128))[tid];
      h127[tid] = packh2(hv.x, hv.y);
    } else {
      int sprev = d ? (511 - (chunk * 128 - 1)) : (chunk * 128 - 1);
      h127[tid] = hh[((size_t)(d * 512 + sprev) * 128 + b) * 64 + tid];
    }
  }
  const ushort* gxp = (const ushort*)gatex + (size_t)d * 8388608 +
                      (size_t)b * 512 + 4 * cx.m + cx.kq;

  ushort g0 = gxp[0];
  ushort g1 = gxp[(size_t)1 * 65536];
  ushort g2 = gxp[(size_t)2 * 65536];
  ushort g3 = gxp[(size_t)3 * 65536];
  __syncthreads();

  for (int tl = 0; tl < 128; tl += 4) {
    int i0 = tl + 4 > 127 ? 127 : tl + 4;
    int i1 = tl + 5 > 127 ? 127 : tl + 5;
    int i2 = tl + 6 > 127 ? 127 : tl + 6;
    int i3 = tl + 7 > 127 ? 127 : tl + 7;
    ushort n0 = gxp[(size_t)i0 * 65536];
    ushort n1 = gxp[(size_t)i1 * 65536];
    ushort n2 = gxp[(size_t)i2 * 65536];
    ushort n3 = gxp[(size_t)i3 * 65536];
    lstm_step(cx, hist, (tl + 127) & 127, tl + 0, g0, c);
    lstm_step(cx, hist, (tl + 0) & 127, tl + 1, g1, c);
    lstm_step(cx, hist, (tl + 1) & 127, tl + 2, g2, c);
    lstm_step(cx, hist, (tl + 2) & 127, tl + 3, g3, c);
    g0 = n0; g1 = n1; g2 = n2; g3 = n3;
  }

  if (cx.kq == 0) statec[(size_t)(d * 128 + b) * 128 + cx.m] = c;

  int base = chunk * 128;
  for (int i = tid; i < 2048; i += 512) {
    int sl2 = i >> 4, q4 = i & 15;
    int s = d ? (511 - (base + sl2)) : (base + sl2);
    *(uint4*)(&hh[((size_t)(d * 512 + s) * 128 + b) * 64 + q4 * 4]) =
        *(const uint4*)((const uint*)&hist[sl2][0] + q4 * 4);
  }
}

// ---------------------------------------------------------------------------
// All-timestep lstm (big-ws path; verified 293-296us).
// ---------------------------------------------------------------------------
__global__ __attribute__((amdgpu_waves_per_eu(2, 2))) __launch_bounds__(512)
void lstm_all_kernel(
    const uint* __restrict__ gatex, const uint* __restrict__ whh,
    const float* __restrict__ h0, const float* __restrict__ c0,
    uint* __restrict__ hh)
{
  const int wg = blockIdx.x;
  const int d = wg >> 7, b = wg & 127;
  const int tid = threadIdx.x;

  __shared__ __align__(16) __fp16 hist[128][128];
  LstmCtx cx;
  lstm_init(cx, whh, d, tid);

  float c = c0[(size_t)(d * 128 + b) * 128 + cx.m];

  if (tid < 64) {
    uint* h127 = (uint*)&hist[127][0];
    float2 hv = ((const float2*)(h0 + (size_t)(d * 128 + b) * 128))[tid];
    h127[tid] = packh2(hv.x, hv.y);
  }
  const ushort* gxp = (const ushort*)gatex + (size_t)d * 33554432 +
                      (size_t)b * 512 + 4 * cx.m + cx.kq;

  ushort g0 = gxp[0];
  ushort g1 = gxp[(size_t)1 * 65536];
  ushort g2 = gxp[(size_t)2 * 65536];
  ushort g3 = gxp[(size_t)3 * 65536];
  __syncthreads();

  for (int tl = 0; tl < 512; tl += 4) {
    int i0 = tl + 4 > 511 ? 511 : tl + 4;
    int i1 = tl + 5 > 511 ? 511 : tl + 5;
    int i2 = tl + 6 > 511 ? 511 : tl + 6;
    int i3 = tl + 7 > 511 ? 511 : tl + 7;
    ushort n0 = gxp[(size_t)i0 * 65536];
    ushort n1 = gxp[(size_t)i1 * 65536];
    ushort n2 = gxp[(size_t)i2 * 65536];
    ushort n3 = gxp[(size_t)i3 * 65536];
    lstm_step(cx, hist, (tl + 127) & 127, (tl + 0) & 127, g0, c);
    lstm_step(cx, hist, (tl + 0) & 127, (tl + 1) & 127, g1, c);
    lstm_step(cx, hist, (tl + 1) & 127, (tl + 2) & 127, g2, c);
    lstm_step(cx, hist, (tl + 2) & 127, (tl + 3) & 127, g3, c);
    g0 = n0; g1 = n1; g2 = n2; g3 = n3;

    if (((tl + 3) & 127) == 127) {
      int base = ((tl + 3) >> 7) * 128;
      for (int i = tid; i < 2048; i += 512) {
        int sl2 = i >> 4, q4 = i & 15;
        int s = d ? (511 - (base + sl2)) : (base + sl2);
        *(uint4*)(&hh[((size_t)(d * 512 + s) * 128 + b) * 64 + q4 * 4]) =
            *(const uint4*)((const uint*)&hist[sl2][0] + q4 * 4);
      }
      __syncthreads();
    }
  }
}

// ---------------------------------------------------------------------------
// Output projection — MFMA GEMM [65536x256]x[256x32], zero LDS (verified).
// ---------------------------------------------------------------------------
__global__ __launch_bounds__(256) void outproj_kernel(
    const uint* __restrict__ hh, const uint* __restrict__ woutp,
    const float* __restrict__ bout, float* __restrict__ feats)
{
  int tid = threadIdx.x;
  int w = tid >> 6, lane = tid & 63;
  int q = lane >> 4, c = lane & 15;
  int row0 = blockIdx.x * 64 + w * 16;

  const uint4* wp4 = (const uint4*)woutp;
  uint4 bf0[8], bf1[8];
#pragma unroll
  for (int ks = 0; ks < 8; ++ks) {
    bf0[ks] = wp4[(size_t)c * 32 + ks * 4 + q];
    bf1[ks] = wp4[(size_t)(16 + c) * 32 + ks * 4 + q];
  }

  int rr = row0 + c;
  int br = rr >> 9, sr = rr & 511;
  const uint4* af4 = (const uint4*)(hh + ((size_t)(sr * BATCH + br)) * 64);
  const uint4* ab4 = (const uint4*)(hh + ((size_t)((SEQ + sr) * BATCH + br)) * 64);

  floatx4 acc0 = (floatx4){0.f, 0.f, 0.f, 0.f};
  floatx4 acc1 = (floatx4){0.f, 0.f, 0.f, 0.f};
#pragma unroll
  for (int ks = 0; ks < 8; ++ks) {
    uint4 a = (ks < 4) ? af4[ks * 4 + q] : ab4[(ks - 4) * 4 + q];
    half8_t af = __builtin_bit_cast(half8_t, a);
    acc0 = __builtin_amdgcn_mfma_f32_16x16x32_f16(
        af, __builtin_bit_cast(half8_t, bf0[ks]), acc0, 0, 0, 0);
    acc1 = __builtin_amdgcn_mfma_f32_16x16x32_f16(
        af, __builtin_bit_cast(half8_t, bf1[ks]), acc1, 0, 0, 0);
  }

  float bb0 = bout[c], bb1 = bout[16 + c];
#pragma unroll
  for (int reg = 0; reg < 4; ++reg) {
    int orow = row0 + q * 4 + reg;
    feats[(size_t)orow * 32 + c] = acc0[reg] + bb0;
    feats[(size_t)orow * 32 + 16 + c] = acc1[reg] + bb1;
  }
}

// ---------------------------------------------------------------------------
// CRF stage A (verified)
// ---------------------------------------------------------------------------
__global__ __launch_bounds__(64) void crf_seg_kernel(
    const float* __restrict__ feats, const float* __restrict__ trans,
    uint* __restrict__ segP, float* __restrict__ segL)
{
  const float L2E = 1.4426950408889634f;
  int blk = blockIdx.x;
  int b = blk >> 5, j = blk & 31;
  int tstart = 1 + 16 * j;
  int nsteps = (j == 31) ? 15 : 16;
  int lane = threadIdx.x;
  int c = lane & 15, q = lane >> 4;

  half8_t afr[2];
#pragma unroll
  for (int rt = 0; rt < 2; ++rt) {
    const float* trow = trans + (rt * 16 + c) * 32 + q * 8;
    float e[8];
#pragma unroll
    for (int i = 0; i < 8; ++i) e[i] = fexp2(trow[i] * L2E);
    uint4 u;
    u.x = packh2(e[0], e[1]); u.y = packh2(e[2], e[3]);
    u.z = packh2(e[4], e[5]); u.w = packh2(e[6], e[7]);
    afr[rt] = __builtin_bit_cast(half8_t, u);
  }
  half8_t bfr[2];
#pragma unroll
  for (int ct = 0; ct < 2; ++ct) {
    uint4 u;
    uint vals[8];
#pragma unroll
    for (int i = 0; i < 8; ++i)
      vals[i] = ((q * 8 + i) == (ct * 16 + c)) ? 0x3C00u : 0u;
    u.x = vals[0] | (vals[1] << 16);
    u.y = vals[2] | (vals[3] << 16);
    u.z = vals[4] | (vals[5] << 16);
    u.w = vals[6] | (vals[7] << 16);
    bfr[ct] = __builtin_bit_cast(half8_t, u);
  }

  __shared__ __fp16 P16[32 * 36];

  const float* fb = feats + ((size_t)b * SEQ + tstart) * NTAG;
  float Lacc = 0.f;
  float4 pre0 = *(const float4*)(fb + q * 4);
  float4 pre1 = *(const float4*)(fb + 16 + q * 4);

  for (int s = 0; s < nsteps; ++s) {
    float4 f0 = pre0, f1 = pre1;
    if (s + 1 < nsteps) {
      pre0 = *(const float4*)(fb + (s + 1) * 32 + q * 4);
      pre1 = *(const float4*)(fb + (s + 1) * 32 + 16 + q * 4);
    }
    floatx4 z4 = (floatx4){0.f, 0.f, 0.f, 0.f};
    floatx4 c00 = __builtin_amdgcn_mfma_f32_16x16x32_f16(afr[0], bfr[0], z4, 0, 0, 0);
    floatx4 c01 = __builtin_amdgcn_mfma_f32_16x16x32_f16(afr[0], bfr[1], z4, 0, 0, 0);
    floatx4 c10 = __builtin_amdgcn_mfma_f32_16x16x32_f16(afr[1], bfr[0], z4, 0, 0, 0);
    floatx4 c11 = __builtin_amdgcn_mfma_f32_16x16x32_f16(afr[1], bfr[1], z4, 0, 0, 0);
    float pf0[4], pf1[4];
    pf0[0] = fexp2(f0.x * L2E); pf0[1] = fexp2(f0.y * L2E);
    pf0[2] = fexp2(f0.z * L2E); pf0[3] = fexp2(f0.w * L2E);
    pf1[0] = fexp2(f1.x * L2E); pf1[1] = fexp2(f1.y * L2E);
    pf1[2] = fexp2(f1.z * L2E); pf1[3] = fexp2(f1.w * L2E);
    float v00[4], v01[4], v10[4], v11[4];
#pragma unroll
    for (int rg = 0; rg < 4; ++rg) {
      v00[rg] = c00[rg] * pf0[rg];
      v01[rg] = c01[rg] * pf0[rg];
      v10[rg] = c10[rg] * pf1[rg];
      v11[rg] = c11[rg] * pf1[rg];
    }
    float mx = 0.f;
#pragma unroll
    for (int rg = 0; rg < 4; ++rg)
      mx = fmaxf(mx, fmaxf(fmaxf(v00[rg], v01[rg]), fmaxf(v10[rg], v11[rg])));
    uint ub = (uint)__builtin_amdgcn_readfirstlane((int)__builtin_bit_cast(uint, mx));
    int e = (int)((ub >> 23) & 255u);
    Lacc += (float)(e - 127);
    float sc = __builtin_bit_cast(float, (uint)((254 - e) << 23));

    __syncthreads();
    {
      uint2 wv2;
      wv2.x = packh2(v00[0] * sc, v00[1] * sc);
      wv2.y = packh2(v00[2] * sc, v00[3] * sc);
      *(uint2*)(&P16[c * 36 + q * 4]) = wv2;
      wv2.x = packh2(v10[0] * sc, v10[1] * sc);
      wv2.y = packh2(v10[2] * sc, v10[3] * sc);
      *(uint2*)(&P16[c * 36 + 16 + q * 4]) = wv2;
      wv2.x = packh2(v01[0] * sc, v01[1] * sc);
      wv2.y = packh2(v01[2] * sc, v01[3] * sc);
      *(uint2*)(&P16[(16 + c) * 36 + q * 4]) = wv2;
      wv2.x = packh2(v11[0] * sc, v11[1] * sc);
      wv2.y = packh2(v11[2] * sc, v11[3] * sc);
      *(uint2*)(&P16[(16 + c) * 36 + 16 + q * 4]) = wv2;
    }
    __syncthreads();
    {
      uint2 lo0 = *(const uint2*)(&P16[c * 36 + q * 8]);
      uint2 hi0 = *(const uint2*)(&P16[c * 36 + q * 8 + 4]);
      uint4 u0; u0.x = lo0.x; u0.y = lo0.y; u0.z = hi0.x; u0.w = hi0.y;
      bfr[0] = __builtin_bit_cast(half8_t, u0);
      uint2 lo1 = *(const uint2*)(&P16[(16 + c) * 36 + q * 8]);
      uint2 hi1 = *(const uint2*)(&P16[(16 + c) * 36 + q * 8 + 4]);
      uint4 u1; u1.x = lo1.x; u1.y = lo1.y; u1.z = hi1.x; u1.w = hi1.y;
      bfr[1] = __builtin_bit_cast(half8_t, u1);
    }
  }
  __syncthreads();
  uint* gp = segP + (size_t)blk * 512;
  if (lane < 32) {
    int i = lane;
#pragma unroll
    for (int tp = 0; tp < 16; ++tp) {
      uint lo = (uint)__builtin_bit_cast(unsigned short, P16[(2 * tp) * 36 + i]);
      uint hi = (uint)__builtin_bit_cast(unsigned short, P16[(2 * tp + 1) * 36 + i]);
      gp[i * 16 + tp] = lo | (hi << 16);
    }
  }
  if (lane == 0) segL[blk] = Lacc;
}

// ---------------------------------------------------------------------------
// CRF stage B + numerator merged (verified)
// ---------------------------------------------------------------------------
__global__ __launch_bounds__(64) void crf_comb_kernel(
    const int* __restrict__ tags, const float* __restrict__ feats,
    const float* __restrict__ trans, const uint* __restrict__ segP,
    const float* __restrict__ segL, float* __restrict__ num,
    float* __restrict__ den)
{
  const float L2E = 1.4426950408889634f, LN2 = 0.6931471805599453f;
  int b = blockIdx.x, l = threadIdx.x;

  {
    const int* tb = tags + b * SEQ;
    float acc = 0.f;
    for (int s = l; s < SEQ; s += 64) {
      int tg = tb[s];
      int pv = (s == 0) ? START_TAG : tb[s - 1];
      acc += trans[pv * NTAG + tg] + feats[((size_t)b * SEQ + s) * NTAG + tg];
    }
#pragma unroll
    for (int msk = 1; msk < 64; msk <<= 1) acc += __shfl_xor(acc, msk);
    if (l == 0) num[b] = acc + trans[tb[SEQ - 1] * NTAG + END_TAG];
  }

  int i = l & 31, hp = l >> 5;
  const float* fb = feats + (size_t)b * SEQ * NTAG;

  float sT = 0.f;
  for (int p = 0; p < 32; ++p) sT += fexp2(trans[i * 32 + p] * L2E);
  float v = (1.f + sT) * fexp2(fb[i] * L2E);
  float L = -10000.f * L2E;

  float vo = __shfl_xor(v, 1);
  uint pv = (i & 1) ? packh2(vo, v) : packh2(v, vo);

  const uint* gp0 = segP + (size_t)b * 32 * 512 + i * 16 + hp * 8;
  uint4 ra = *(const uint4*)(gp0);
  uint4 rb = *(const uint4*)(gp0 + 4);

  for (int seg = 0; seg < 32; ++seg) {
    uint4 ca = ra, cb = rb;
    if (seg + 1 < 32) {
      ra = *(const uint4*)(gp0 + (seg + 1) * 512);
      rb = *(const uint4*)(gp0 + (seg + 1) * 512 + 4);
    }
    float g0 = __shfl(__builtin_bit_cast(float, pv), hp * 16 + 0);
    float g1 = __shfl(__builtin_bit_cast(float, pv), hp * 16 + 2);
    float g2 = __shfl(__builtin_bit_cast(float, pv), hp * 16 + 4);
    float g3 = __shfl(__builtin_bit_cast(float, pv), hp * 16 + 6);
    float g4 = __shfl(__builtin_bit_cast(float, pv), hp * 16 + 8);
    float g5 = __shfl(__builtin_bit_cast(float, pv), hp * 16 + 10);
    float g6 = __shfl(__builtin_bit_cast(float, pv), hp * 16 + 12);
    float g7 = __shfl(__builtin_bit_cast(float, pv), hp * 16 + 14);
    float acc = 0.f;
    acc = fdot2(__builtin_bit_cast(uint, g0), ca.x, acc);
    acc = fdot2(__builtin_bit_cast(uint, g1), ca.y, acc);
    acc = fdot2(__builtin_bit_cast(uint, g2), ca.z, acc);
    acc = fdot2(__builtin_bit_cast(uint, g3), ca.w, acc);
    acc = fdot2(__builtin_bit_cast(uint, g4), cb.x, acc);
    acc = fdot2(__builtin_bit_cast(uint, g5), cb.y, acc);
    acc = fdot2(__builtin_bit_cast(uint, g6), cb.z, acc);
    acc = fdot2(__builtin_bit_cast(uint, g7), cb.w, acc);
    float sm = acc + __shfl_xor(acc, 32);
    uint ub = (uint)__builtin_amdgcn_readfirstlane((int)__builtin_bit_cast(uint, sm));
    int e = (int)((ub >> 23) & 255u);
    L += (float)(e - 127) + segL[b * 32 + seg];
    float sc = __builtin_bit_cast(float, (uint)((254 - e) << 23));
    v = sm * sc;
    float vo2 = __shfl_xor(v, 1);
    pv = (i & 1) ? packh2(vo2, v) : packh2(v, vo2);
  }
  float wv = v * fexp2(trans[i * 32 + END_TAG] * L2E);
#pragma unroll
  for (int msk = 1; msk <= 16; msk <<= 1) wv += __shfl_xor(wv, msk);
  if (l == 0) den[b] = (L + flog2(wv)) * LN2;
}

__global__ __launch_bounds__(128) void final_kernel(
    const float* __restrict__ num, const float* __restrict__ den,
    float* __restrict__ out)
{
  int tid = threadIdx.x;
  float v = num[tid] - den[tid];
#pragma unroll
  for (int msk = 1; msk < 64; msk <<= 1) v += __shfl_xor(v, msk);
  __shared__ float tmp[2];
  if ((tid & 63) == 0) tmp[tid >> 6] = v;
  __syncthreads();
  if (tid == 0) out[0] = (tmp[0] + tmp[1]) * (1.f / 128.f);
}

// ---------------------------------------------------------------------------
// Workspace layouts (same as R23).
// ---------------------------------------------------------------------------
extern "C" void kernel_launch(void* const* d_in, const int* in_sizes, int n_in,
                              void* d_out, int out_size, void* d_ws, size_t ws_size,
                              hipStream_t stream)
{
  const int* sentence = (const int*)d_in[0];
  const int* tags = (const int*)d_in[1];
  const float* embed = (const float*)d_in[2];
  const float* Wihf = (const float*)d_in[3];
  const float* Whhf = (const float*)d_in[4];
  const float* bihf = (const float*)d_in[5];
  const float* bhhf = (const float*)d_in[6];
  const float* Wihb = (const float*)d_in[7];
  const float* Whhb = (const float*)d_in[8];
  const float* bihb = (const float*)d_in[9];
  const float* bhhb = (const float*)d_in[10];
  const float* Wout = (const float*)d_in[11];
  const float* bout = (const float*)d_in[12];
  const float* trans = (const float*)d_in[13];
  const float* h0 = (const float*)d_in[14];
  const float* c0 = (const float*)d_in[15];
  float* out = (float*)d_out;

  char* ws = (char*)d_ws;
  uint* wihI = (uint*)(ws + 0);
  uint* whh = (uint*)(ws + 262144);
  uint* woutp = (uint*)(ws + 524288);
  float* biasI = (float*)(ws + 540672);
  float* numb = (float*)(ws + 544768);
  float* denb = (float*)(ws + 545280);
  float* statec = (float*)(ws + 545792);
  int* sentT = (int*)(ws + 700416);
  uint* hh = (uint*)(ws + 1048576);
  uint* embH = (uint*)(ws + 1048576);   // overlays hh; dead before lstm
  uint* gatex = (uint*)(ws + 34603008);
  float* feats = (float*)(ws + 34603008);
  uint* segP = (uint*)(ws + 42991616);
  float* segL = (float*)(ws + 51380224);

  hipLaunchKernelGGL(prep_kernel, dim3(8980), dim3(256), 0, stream,
                     Wihf, Whhf, bihf, bhhf, Wihb, Whhb, bihb, bhhb, Wout,
                     sentence, embed, wihI, whh, woutp, biasI, sentT, embH);

  bool big = ws_size >= 168820736ull;
  if (big) {
    hipLaunchKernelGGL(gemmx_all_kernel, dim3(4096), dim3(256), 0, stream,
                       sentT, embH, wihI, biasI, gatex);
    hipLaunchKernelGGL(lstm_all_kernel, dim3(256), dim3(512), 0, stream,
                       gatex, whh, h0, c0, hh);
  } else {
    for (int c = 0; c < 4; ++c) {
      hipLaunchKernelGGL(gemmx_kernel, dim3(1024), dim3(256), 0, stream,
                         sentT, embed, wihI, biasI, gatex, c);
      hipLaunchKernelGGL(lstm_kernel, dim3(256), dim3(512), 0, stream,
                         gatex, whh, h0, c0, statec, hh, c);
    }
  }

  hipLaunchKernelGGL(outproj_kernel, dim3(1024), dim3(256), 0, stream,
                     hh, woutp, bout, feats);
  hipLaunchKernelGGL(crf_seg_kernel, dim3(4096), dim3(64), 0, stream,
                     feats, trans, segP, segL);
  hipLaunchKernelGGL(crf_comb_kernel, dim3(128), dim3(64), 0, stream,
                     tags, feats, trans, segP, segL, numb, denb);
  hipLaunchKernelGGL(final_kernel, dim3(1), dim3(128), 0, stream,
                     numb, denb, out);
}